// Round 2
// baseline (72.902 us; speedup 1.0000x reference)
//
#include <hip/hip_runtime.h>
#include <math.h>

// Problem constants (fixed by reference setup_inputs): x [2,3,512,512] f32.
#define BC 6
#define H_ 512
#define W_ 512
#define HW (H_ * W_)
#define EPS 1e-6f
#define EXPM05 0.60653065971263342f  // exp(-0.5)

#define BXT 64          // threads in x (one wave per row of threads)
#define BYT 4           // threads in y
#define NPY 4           // output rows per thread
#define TILE_W (BXT + 8)     // 72
#define TILE_H (BYT * NPY + 8) // 24
#define TSTR 28         // padded transposed row stride in floats (112 B = 7*16 B)

__global__ __launch_bounds__(256) void texmart_kernel(const float* __restrict__ x,
                                                      float* __restrict__ out) {
    // Transposed tiles: [col][row]. Row base = col*112 B (16-B aligned).
    __shared__ __align__(16) float xs[TILE_W][TSTR];
    __shared__ __align__(16) float pq[TILE_W][TSTR];  // p*log(p+EPS)

    const int tx = threadIdx.x, ty = threadIdx.y;
    const int bx = blockIdx.x * BXT, by = blockIdx.y * (BYT * NPY);
    const int plane = blockIdx.z;
    const float* __restrict__ xp = x + (size_t)plane * HW;

    // --- Stage tile + halo (zero pad), precompute p*log(p+EPS).
    const int tid = ty * BXT + tx;
    for (int idx = tid; idx < TILE_W * TILE_H; idx += BXT * BYT) {
        const int t = idx / TILE_W;          // tile row 0..23
        const int c = idx - t * TILE_W;      // tile col 0..71
        const int gy = by + t - 4, gx = bx + c - 4;
        float v = 0.0f;
        if (gy >= 0 && gy < H_ && gx >= 0 && gx < W_) v = xp[gy * W_ + gx];
        xs[c][t] = v;
        pq[c][t] = v * __logf(v + EPS);
    }
    __syncthreads();

    const int ty4 = ty * NPY;   // this thread's first tile row (halo-relative 0)

    // ---------------- Pass 1: separable sums via vertical prefix ----------------
    // cS*[o][R-1] accumulate full (2R+1)^2 window sums for output row o.
    float cS1[NPY][4], cS2[NPY][4], cSL[NPY][4];
#pragma unroll
    for (int o = 0; o < NPY; ++o)
#pragma unroll
        for (int R = 0; R < 4; ++R) { cS1[o][R] = 0.f; cS2[o][R] = 0.f; cSL[o][R] = 0.f; }

#pragma unroll
    for (int dj = 0; dj < 9; ++dj) {
        const int a = dj < 4 ? 4 - dj : dj - 4;          // |dj-4|, compile-time
        const int c = tx + dj;
        const float4 A = *(const float4*)&xs[c][ty4 + 0];
        const float4 Bv = *(const float4*)&xs[c][ty4 + 4];
        const float4 Cv = *(const float4*)&xs[c][ty4 + 8];
        const float4 Aq = *(const float4*)&pq[c][ty4 + 0];
        const float4 Bq = *(const float4*)&pq[c][ty4 + 4];
        const float4 Cq = *(const float4*)&pq[c][ty4 + 8];
        const float p[12] = {A.x, A.y, A.z, A.w, Bv.x, Bv.y, Bv.z, Bv.w, Cv.x, Cv.y, Cv.z, Cv.w};
        const float q[12] = {Aq.x, Aq.y, Aq.z, Aq.w, Bq.x, Bq.y, Bq.z, Bq.w, Cq.x, Cq.y, Cq.z, Cq.w};

        float P1[13], P2[13], PL[13];
        P1[0] = 0.f; P2[0] = 0.f; PL[0] = 0.f;
#pragma unroll
        for (int k = 0; k < 12; ++k) {
            P1[k + 1] = P1[k] + p[k];
            P2[k + 1] = __fmaf_rn(p[k], p[k], P2[k]);
            PL[k + 1] = PL[k] + q[k];
        }

#pragma unroll
        for (int o = 0; o < NPY; ++o) {
#pragma unroll
            for (int R = 1; R <= 4; ++R) {
                if (R >= a) {
                    // vertical window rows [o+4-R, o+4+R] -> P[o+5+R]-P[o+4-R]
                    cS1[o][R - 1] += P1[o + 5 + R] - P1[o + 4 - R];
                    cS2[o][R - 1] += P2[o + 5 + R] - P2[o + 4 - R];
                    cSL[o][R - 1] += PL[o + 5 + R] - PL[o + 4 - R];
                }
            }
        }
    }

    // Means per (o, R); cS1 no longer needed afterwards (S1*m == K*m*m).
    float mean[NPY][4];
#pragma unroll
    for (int o = 0; o < NPY; ++o) {
        mean[o][0] = cS1[o][0] * (1.f / 9.f);
        mean[o][1] = cS1[o][1] * (1.f / 25.f);
        mean[o][2] = cS1[o][2] * (1.f / 49.f);
        mean[o][3] = cS1[o][3] * (1.f / 81.f);
    }

    // ---------------- Pass 2: homogeneity sums  Σ|p - mean_R| ----------------
    float sa[NPY][4];
#pragma unroll
    for (int o = 0; o < NPY; ++o)
#pragma unroll
        for (int R = 0; R < 4; ++R) sa[o][R] = 0.f;

#pragma unroll
    for (int dj = 0; dj < 9; ++dj) {
        const int a = dj < 4 ? 4 - dj : dj - 4;
        const int c = tx + dj;
        const float4 A = *(const float4*)&xs[c][ty4 + 0];
        const float4 Bv = *(const float4*)&xs[c][ty4 + 4];
        const float4 Cv = *(const float4*)&xs[c][ty4 + 8];
        const float p[12] = {A.x, A.y, A.z, A.w, Bv.x, Bv.y, Bv.z, Bv.w, Cv.x, Cv.y, Cv.z, Cv.w};

#pragma unroll
        for (int o = 0; o < NPY; ++o) {
#pragma unroll
            for (int k = 0; k < 9; ++k) {
                const int adi = k < 4 ? 4 - k : k - 4;   // |di|
                const int r0l = adi > a ? adi : a;
                const int r0 = r0l < 1 ? 1 : r0l;
#pragma unroll
                for (int R = r0; R <= 4; ++R) {
                    sa[o][R - 1] += fabsf(p[o + k] - mean[o][R - 1]);
                }
            }
        }
    }

    // ---------------- Epilogue ----------------
    const int gxx = bx + tx;
#pragma unroll
    for (int o = 0; o < NPY; ++o) {
        const int oy = by + ty4 + o;
        float* __restrict__ orow = out + (size_t)plane * 16 * HW + (size_t)oy * W_ + gxx;
#pragma unroll
        for (int R = 1; R <= 4; ++R) {
            const float K = (float)((2 * R + 1) * (2 * R + 1));
            const float invK = 1.f / K;
            const float invKm1 = 1.f / (K - 1.f);
            const float m = mean[o][R - 1];
            const float S2 = cS2[o][R - 1];
            float S2c = S2 - K * m * m;          // Σ(p-mean)^2
            if (S2c < 0.f) S2c = 0.f;
            const float varK = S2c * invK;
            const float sd = sqrtf(S2c * invKm1) + EPS;   // ddof=1 std + EPS
            const float contrast = varK * __frcp_rn(sd * sd);
            const float energy = S2 * invK;
            const float entropy = -cSL[o][R - 1] * invK;
            const float homog = __frcp_rn(1.f + sa[o][R - 1] * invK);

            float* __restrict__ o4 = orow + (size_t)(R - 1) * 4 * HW;
            o4[0 * HW] = (contrast + EPS) * EXPM05;  // exp(log(f+EPS)-0.5) = (f+EPS)e^-0.5
            o4[1 * HW] = (energy + EPS) * EXPM05;
            o4[2 * HW] = (entropy + EPS) * EXPM05;
            o4[3 * HW] = (homog + EPS) * EXPM05;
        }
    }
}

extern "C" void kernel_launch(void* const* d_in, const int* in_sizes, int n_in,
                              void* d_out, int out_size, void* d_ws, size_t ws_size,
                              hipStream_t stream) {
    const float* x = (const float*)d_in[0];
    float* out = (float*)d_out;
    dim3 block(BXT, BYT, 1);
    dim3 grid(W_ / BXT, H_ / (BYT * NPY), BC);
    texmart_kernel<<<grid, block, 0, stream>>>(x, out);
}

// Round 3
// 58.081 us; speedup vs baseline: 1.2552x; 1.2552x over previous
//
#include <hip/hip_runtime.h>
#include <math.h>

// Problem constants (fixed by reference setup_inputs): x [2,3,512,512] f32.
#define BC 6
#define H_ 512
#define W_ 512
#define HW (H_ * W_)
#define EPS 1e-6f
#define EXPM05 0.60653065971263342f  // exp(-0.5)

#define BXT 64     // threads x (one wave per thread-row)
#define BYT 8      // threads y
#define NPY 2      // output rows per thread -> block covers 64 x 16 outputs
#define TW 72      // tile width  (64 + 2*4 halo)
#define TH 24      // tile height (16 + 2*4 halo)
#define PQS 52     // interleaved (p,q) stride in floats: 2*TH + 4 pad (52%4==0 for b128 align)
#define XSS 26     // plain-p stride in floats (even -> b64 align; gcd(26,32)=2 -> conflict-free b64)

__global__ __launch_bounds__(512) void texmart_kernel(const float* __restrict__ x,
                                                      float* __restrict__ out) {
    // Transposed tiles [col][row-interleaved]:
    //   pz[c][2r+0] = p,  pz[c][2r+1] = p*log(p+EPS)
    __shared__ __align__(16) float pz[TW][PQS];
    __shared__ __align__(16) float xs2[TW][XSS];

    const int tx = threadIdx.x, ty = threadIdx.y;
    const int bx = blockIdx.x * BXT, by = blockIdx.y * (BYT * NPY);
    const int plane = blockIdx.z;
    const float* __restrict__ xp = x + (size_t)plane * HW;

    // ---- Stage tile + halo (zero pad), precompute p*log(p+EPS) once per element.
    const int tid = ty * BXT + tx;
    for (int idx = tid; idx < TW * TH; idx += BXT * BYT) {
        const int t = idx / TW;          // tile row 0..23
        const int c = idx - t * TW;      // tile col 0..71
        const int gy = by + t - 4, gx = bx + c - 4;
        float v = 0.0f;
        if (gy >= 0 && gy < H_ && gx >= 0 && gx < W_) v = xp[gy * W_ + gx];
        const float q = v * __logf(v + EPS);   // zero-pad contributes exactly 0
        *(float2*)&pz[c][2 * t] = make_float2(v, q);
        xs2[c][t] = v;
    }
    __syncthreads();

    const int ty2 = ty * NPY;   // first tile row this thread reads (even)

    // ---- Pass 1: separable sums with incremental window widening.
    float cS1[NPY][4], cS2[NPY][4], cSL[NPY][4];
#pragma unroll
    for (int o = 0; o < NPY; ++o)
#pragma unroll
        for (int R = 0; R < 4; ++R) { cS1[o][R] = 0.f; cS2[o][R] = 0.f; cSL[o][R] = 0.f; }

#pragma unroll
    for (int dj = 0; dj < 9; ++dj) {
        const int a = dj < 4 ? 4 - dj : dj - 4;          // compile-time after unroll
        const float* __restrict__ col = &pz[tx + dj][2 * ty2];
        const float4 w0 = *(const float4*)(col + 0);
        const float4 w1 = *(const float4*)(col + 4);
        const float4 w2 = *(const float4*)(col + 8);
        const float4 w3 = *(const float4*)(col + 12);
        const float4 w4 = *(const float4*)(col + 16);
        const float p[10] = {w0.x, w0.z, w1.x, w1.z, w2.x, w2.z, w3.x, w3.z, w4.x, w4.z};
        const float q[10] = {w0.y, w0.w, w1.y, w1.w, w2.y, w2.w, w3.y, w3.w, w4.y, w4.w};

#pragma unroll
        for (int o = 0; o < NPY; ++o) {
            float s1 = p[o + 4];
            float s2 = p[o + 4] * p[o + 4];
            float sl = q[o + 4];
#pragma unroll
            for (int R = 1; R <= 4; ++R) {
                const int lo = o + 4 - R, hi = o + 4 + R;
                s1 += p[lo] + p[hi];
                s2 = __fmaf_rn(p[lo], p[lo], __fmaf_rn(p[hi], p[hi], s2));
                sl += q[lo] + q[hi];
                if (R >= a) {   // this column participates in window R
                    cS1[o][R - 1] += s1;
                    cS2[o][R - 1] += s2;
                    cSL[o][R - 1] += sl;
                }
            }
        }
    }

    float mean[NPY][4];
#pragma unroll
    for (int o = 0; o < NPY; ++o) {
        mean[o][0] = cS1[o][0] * (1.f / 9.f);
        mean[o][1] = cS1[o][1] * (1.f / 25.f);
        mean[o][2] = cS1[o][2] * (1.f / 49.f);
        mean[o][3] = cS1[o][3] * (1.f / 81.f);
    }

    // ---- Pass 2: homogeneity sums  Σ|p - mean_R|  (mean differs per window).
    float sa[NPY][4];
#pragma unroll
    for (int o = 0; o < NPY; ++o)
#pragma unroll
        for (int R = 0; R < 4; ++R) sa[o][R] = 0.f;

#pragma unroll
    for (int dj = 0; dj < 9; ++dj) {
        const int a = dj < 4 ? 4 - dj : dj - 4;
        const float* __restrict__ col = &xs2[tx + dj][ty2];
        const float2 u0 = *(const float2*)(col + 0);
        const float2 u1 = *(const float2*)(col + 2);
        const float2 u2 = *(const float2*)(col + 4);
        const float2 u3 = *(const float2*)(col + 6);
        const float2 u4 = *(const float2*)(col + 8);
        const float p[10] = {u0.x, u0.y, u1.x, u1.y, u2.x, u2.y, u3.x, u3.y, u4.x, u4.y};

#pragma unroll
        for (int o = 0; o < NPY; ++o) {
#pragma unroll
            for (int k = 0; k < 9; ++k) {
                const int adi = k < 4 ? 4 - k : k - 4;
                const int rm = a > adi ? a : adi;
                const int r0 = rm < 1 ? 1 : rm;          // compile-time
#pragma unroll
                for (int R = 1; R <= 4; ++R) {
                    if (R >= r0) sa[o][R - 1] += fabsf(p[o + k] - mean[o][R - 1]);
                }
            }
        }
    }

    // ---- Epilogue.
    const int gxx = bx + tx;
#pragma unroll
    for (int o = 0; o < NPY; ++o) {
        const int oy = by + ty2 + o;
        float* __restrict__ orow = out + (size_t)plane * 16 * HW + (size_t)oy * W_ + gxx;
#pragma unroll
        for (int R = 1; R <= 4; ++R) {
            const float K = (float)((2 * R + 1) * (2 * R + 1));
            const float invK = 1.f / K;
            const float invKm1 = 1.f / (K - 1.f);
            const float m = mean[o][R - 1];
            const float S2 = cS2[o][R - 1];
            float S2c = __fmaf_rn(-cS1[o][R - 1], m, S2);   // Σ(p-mean)^2
            if (S2c < 0.f) S2c = 0.f;
            const float varK = S2c * invK;
            const float sd = sqrtf(S2c * invKm1) + EPS;     // ddof=1 std + EPS
            const float contrast = varK * __frcp_rn(sd * sd);
            const float energy = S2 * invK;
            const float entropy = -cSL[o][R - 1] * invK;
            const float homog = __frcp_rn(1.f + sa[o][R - 1] * invK);

            float* __restrict__ o4 = orow + (size_t)(R - 1) * 4 * HW;
            o4[0 * HW] = (contrast + EPS) * EXPM05;  // exp(log(f+EPS)-0.5) = (f+EPS)e^-0.5
            o4[1 * HW] = (energy + EPS) * EXPM05;
            o4[2 * HW] = (entropy + EPS) * EXPM05;
            o4[3 * HW] = (homog + EPS) * EXPM05;
        }
    }
}

extern "C" void kernel_launch(void* const* d_in, const int* in_sizes, int n_in,
                              void* d_out, int out_size, void* d_ws, size_t ws_size,
                              hipStream_t stream) {
    const float* x = (const float*)d_in[0];
    float* out = (float*)d_out;
    dim3 block(BXT, BYT, 1);
    dim3 grid(W_ / BXT, H_ / (BYT * NPY), BC);
    texmart_kernel<<<grid, block, 0, stream>>>(x, out);
}